// Round 1
// baseline (7020.886 us; speedup 1.0000x reference)
//
#include <hip/hip_runtime.h>

#define B_ 4
#define S_ 2048
#define D_ 512
#define H_ 8
#define DK_ 64
#define M_ (B_*S_)   // 8192 rows

// ---------------------------------------------------------------------------
// Tiled fp32 GEMM: Y[M,512] = X[M,512] @ W[512,512]^T + bias
// head_layout=1: write Y in [B,H,S,DK] layout (for q/k/v head split)
// head_layout=0: write Y as plain [M,512]
// Tile 64x64, 256 threads, each thread 4x4 outputs, K-tile 16.
// ---------------------------------------------------------------------------
__global__ __launch_bounds__(256) void proj_kernel(
    const float* __restrict__ X, const float* __restrict__ W,
    const float* __restrict__ bias, float* __restrict__ Y, int head_layout)
{
    // +4 pad keeps rows 16B-aligned for float4 LDS reads (68*4 = 272 = 17*16)
    __shared__ float As[16][68];
    __shared__ float Bs[16][68];
    const int tid = threadIdx.x;
    const int m0 = blockIdx.x * 64;
    const int n0 = blockIdx.y * 64;
    const int tx = tid & 15, ty = tid >> 4;
    const int ml = tid >> 2;          // 0..63 tile row
    const int kl = (tid & 3) * 4;     // 0,4,8,12 k offset

    float acc[4][4] = {};
    for (int kt = 0; kt < D_; kt += 16) {
        float4 a  = *(const float4*)(X + (size_t)(m0 + ml) * D_ + kt + kl);
        float4 b4 = *(const float4*)(W + (size_t)(n0 + ml) * D_ + kt + kl);
        As[kl+0][ml] = a.x;  As[kl+1][ml] = a.y;  As[kl+2][ml] = a.z;  As[kl+3][ml] = a.w;
        Bs[kl+0][ml] = b4.x; Bs[kl+1][ml] = b4.y; Bs[kl+2][ml] = b4.z; Bs[kl+3][ml] = b4.w;
        __syncthreads();
        #pragma unroll
        for (int k = 0; k < 16; ++k) {
            float4 av = *(const float4*)&As[k][ty * 4];
            float4 bv = *(const float4*)&Bs[k][tx * 4];
            float ar[4] = {av.x, av.y, av.z, av.w};
            float br[4] = {bv.x, bv.y, bv.z, bv.w};
            #pragma unroll
            for (int i = 0; i < 4; ++i)
                #pragma unroll
                for (int j = 0; j < 4; ++j)
                    acc[i][j] += ar[i] * br[j];
        }
        __syncthreads();
    }

    #pragma unroll
    for (int i = 0; i < 4; ++i) {
        const int m  = m0 + ty * 4 + i;
        const int bi = m >> 11;        // m / S_
        const int si = m & (S_ - 1);   // m % S_
        #pragma unroll
        for (int j = 0; j < 4; ++j) {
            const int n = n0 + tx * 4 + j;
            const float vv = acc[i][j] + bias[n];
            if (head_layout) {
                const int h  = n >> 6;     // n / DK_
                const int dk = n & 63;     // n % DK_
                Y[(((size_t)bi * H_ + h) * S_ + si) * DK_ + dk] = vv;
            } else {
                Y[(size_t)m * D_ + n] = vv;
            }
        }
    }
}

// ---------------------------------------------------------------------------
// Attention: one block (256 thr) per (b,h,q) row.
// scores row kept in LDS; computes masked scaled QK^T, softmax, writes scores,
// then P@V into concat (already in [B,S,D] layout for the output projection).
// ---------------------------------------------------------------------------
__device__ __forceinline__ float wave_max(float v) {
    #pragma unroll
    for (int o = 32; o > 0; o >>= 1) v = fmaxf(v, __shfl_down(v, o));
    return v;
}
__device__ __forceinline__ float wave_sum(float v) {
    #pragma unroll
    for (int o = 32; o > 0; o >>= 1) v += __shfl_down(v, o);
    return v;
}

__global__ __launch_bounds__(256) void attn_kernel(
    const float* __restrict__ qh, const float* __restrict__ kh,
    const float* __restrict__ vh, const int* __restrict__ mask,
    float* __restrict__ scores, float* __restrict__ concat)
{
    __shared__ float p[S_];
    __shared__ float qs[DK_];
    __shared__ float smax[4], ssum[4];
    __shared__ float red[4][DK_];

    const int tid = threadIdx.x;
    const int qi = blockIdx.x, h = blockIdx.y, b = blockIdx.z;
    const size_t bh = (size_t)b * H_ + h;
    const float* qrow = qh + (bh * S_ + qi) * DK_;
    const float* kb   = kh + bh * S_ * DK_;
    const float* vb   = vh + bh * S_ * DK_;
    const int*   mrow = mask + ((size_t)b * S_ + qi) * S_;

    if (tid < 16) *(float4*)&qs[tid * 4] = *(const float4*)&qrow[tid * 4];
    __syncthreads();

    // ---- scores = (q . k) * 1/sqrt(64), masked ----
    float lmax = -1e30f;
    #pragma unroll
    for (int jj = 0; jj < S_ / 256; ++jj) {
        const int j = jj * 256 + tid;
        const float* kr = kb + (size_t)j * DK_;
        float s = 0.f;
        #pragma unroll
        for (int d = 0; d < DK_; d += 4) {
            float4 kv = *(const float4*)(kr + d);
            s += qs[d] * kv.x + qs[d+1] * kv.y + qs[d+2] * kv.z + qs[d+3] * kv.w;
        }
        s *= 0.125f;
        if (mrow[j] == 0) s = -1e9f;
        p[j] = s;
        lmax = fmaxf(lmax, s);
    }
    lmax = wave_max(lmax);
    if ((tid & 63) == 0) smax[tid >> 6] = lmax;
    __syncthreads();
    const float rmax = fmaxf(fmaxf(smax[0], smax[1]), fmaxf(smax[2], smax[3]));

    // ---- exp + sum ----
    float lsum = 0.f;
    #pragma unroll
    for (int jj = 0; jj < S_ / 256; ++jj) {
        const int j = jj * 256 + tid;
        const float e = __expf(p[j] - rmax);
        p[j] = e;
        lsum += e;
    }
    lsum = wave_sum(lsum);
    if ((tid & 63) == 0) ssum[tid >> 6] = lsum;
    __syncthreads();
    const float inv = 1.f / (ssum[0] + ssum[1] + ssum[2] + ssum[3]);

    // ---- normalize + write scores ----
    float* srow = scores + (bh * S_ + qi) * S_;
    #pragma unroll
    for (int jj = 0; jj < S_ / 256; ++jj) {
        const int j = jj * 256 + tid;
        const float pv = p[j] * inv;
        p[j] = pv;
        srow[j] = pv;
    }
    __syncthreads();

    // ---- P @ V : wave g handles j-range [g*512, (g+1)*512), lane dd = out dim ----
    const int g = tid >> 6, dd = tid & 63;
    float acc = 0.f;
    const float* vcol = vb + dd;
    #pragma unroll 4
    for (int j = g * (S_ / 4); j < (g + 1) * (S_ / 4); ++j)
        acc += p[j] * vcol[(size_t)j * DK_];
    red[g][dd] = acc;
    __syncthreads();
    if (g == 0) {
        const float r = red[0][dd] + red[1][dd] + red[2][dd] + red[3][dd];
        concat[((size_t)b * S_ + qi) * D_ + h * DK_ + dd] = r;
    }
}

// ---------------------------------------------------------------------------
extern "C" void kernel_launch(void* const* d_in, const int* in_sizes, int n_in,
                              void* d_out, int out_size, void* d_ws, size_t ws_size,
                              hipStream_t stream) {
    const float* q  = (const float*)d_in[0];
    const float* k  = (const float*)d_in[1];
    const float* v  = (const float*)d_in[2];
    const int* mask = (const int*)d_in[3];
    const float* Wq = (const float*)d_in[4];  const float* bq = (const float*)d_in[5];
    const float* Wk = (const float*)d_in[6];  const float* bk = (const float*)d_in[7];
    const float* Wv = (const float*)d_in[8];  const float* bv = (const float*)d_in[9];
    const float* Wo = (const float*)d_in[10]; const float* bo = (const float*)d_in[11];

    float* out    = (float*)d_out;                 // [B,S,D]
    float* scores = out + (size_t)B_ * S_ * D_;    // [B,H,S,S]

    const size_t NH = (size_t)B_ * H_ * S_ * DK_;  // 4.19M floats
    float* qh     = (float*)d_ws;                  // [B,H,S,DK]
    float* kh     = qh + NH;
    float* vh     = kh + NH;
    float* concat = vh + NH;                       // [B,S,D]
    // total ws use: 4 * 16.78 MB = 67.1 MB

    dim3 gg(M_ / 64, D_ / 64);   // 128 x 8
    proj_kernel<<<gg, 256, 0, stream>>>(q, Wq, bq, qh, 1);
    proj_kernel<<<gg, 256, 0, stream>>>(k, Wk, bk, kh, 1);
    proj_kernel<<<gg, 256, 0, stream>>>(v, Wv, bv, vh, 1);
    attn_kernel<<<dim3(S_, H_, B_), 256, 0, stream>>>(qh, kh, vh, mask, scores, concat);
    proj_kernel<<<gg, 256, 0, stream>>>(concat, Wo, bo, out, 0);
}

// Round 3
// 1155.213 us; speedup vs baseline: 6.0776x; 6.0776x over previous
//
#include <hip/hip_runtime.h>
#include <hip/hip_bf16.h>

#define B_ 4
#define S_ 2048
#define D_ 512
#define H_ 8
#define DK_ 64
#define M_ (B_*S_)   // 8192 rows

typedef float f32x4 __attribute__((ext_vector_type(4)));
typedef __bf16 bf16x8 __attribute__((ext_vector_type(8)));
typedef unsigned short u16x8 __attribute__((ext_vector_type(8)));

static __device__ __forceinline__ unsigned short f2bf(float x) {
    return __builtin_bit_cast(unsigned short, __float2bfloat16(x));
}
static __device__ __forceinline__ float bf2f(unsigned short u) {
    return __bfloat162float(__builtin_bit_cast(__hip_bfloat16, u));
}
static __device__ __forceinline__ bf16x8 ldfrag(const unsigned short* p) {
    return __builtin_bit_cast(bf16x8, *(const u16x8*)p);
}

// ---------------------------------------------------------------------------
// Tiled fp32 GEMM: Y = X[M,512] @ W[512,512]^T + bias
// mode 0: Yf32 plain [M,512]
// mode 1: Yhi/Ylo bf16 split, head layout [B,H,S,DK]   (q,k)
// mode 2: Yhi bf16 only, head layout                    (v)
// ---------------------------------------------------------------------------
__global__ __launch_bounds__(256) void proj_kernel(
    const float* __restrict__ X, const float* __restrict__ W,
    const float* __restrict__ bias, float* __restrict__ Yf32,
    unsigned short* __restrict__ Yhi, unsigned short* __restrict__ Ylo, int mode)
{
    __shared__ float As[16][68];
    __shared__ float Bs[16][68];
    const int tid = threadIdx.x;
    const int m0 = blockIdx.x * 64;
    const int n0 = blockIdx.y * 64;
    const int tx = tid & 15, ty = tid >> 4;
    const int ml = tid >> 2;
    const int kl = (tid & 3) * 4;

    float acc[4][4] = {};
    for (int kt = 0; kt < D_; kt += 16) {
        float4 a  = *(const float4*)(X + (size_t)(m0 + ml) * D_ + kt + kl);
        float4 b4 = *(const float4*)(W + (size_t)(n0 + ml) * D_ + kt + kl);
        As[kl+0][ml] = a.x;  As[kl+1][ml] = a.y;  As[kl+2][ml] = a.z;  As[kl+3][ml] = a.w;
        Bs[kl+0][ml] = b4.x; Bs[kl+1][ml] = b4.y; Bs[kl+2][ml] = b4.z; Bs[kl+3][ml] = b4.w;
        __syncthreads();
        #pragma unroll
        for (int k = 0; k < 16; ++k) {
            float4 av = *(const float4*)&As[k][ty * 4];
            float4 bv = *(const float4*)&Bs[k][tx * 4];
            float ar[4] = {av.x, av.y, av.z, av.w};
            float br[4] = {bv.x, bv.y, bv.z, bv.w};
            #pragma unroll
            for (int i = 0; i < 4; ++i)
                #pragma unroll
                for (int j = 0; j < 4; ++j)
                    acc[i][j] += ar[i] * br[j];
        }
        __syncthreads();
    }

    #pragma unroll
    for (int i = 0; i < 4; ++i) {
        const int m  = m0 + ty * 4 + i;
        const int bi = m >> 11;
        const int si = m & (S_ - 1);
        #pragma unroll
        for (int j = 0; j < 4; ++j) {
            const int n = n0 + tx * 4 + j;
            const float vv = acc[i][j] + bias[n];
            if (mode == 0) {
                Yf32[(size_t)m * D_ + n] = vv;
            } else {
                const int h  = n >> 6;
                const int dk = n & 63;
                const size_t idx = (((size_t)bi * H_ + h) * S_ + si) * DK_ + dk;
                const unsigned short hi = f2bf(vv);
                Yhi[idx] = hi;
                if (mode == 1) Ylo[idx] = f2bf(vv - bf2f(hi));
            }
        }
    }
}

// ---------------------------------------------------------------------------
// Flash-style two-pass MFMA attention.
// Block = 256 thr (4 waves) handles one (b, h, 64-row q-tile).
// Wave w owns q rows [w*16, w*16+16). MFMA 16x16x32 bf16.
// QK^T uses hi/lo bf16 split (3 MFMAs); PV plain bf16.
// C/D layout: col=lane&15, row=(lane>>4)*4+reg. A/B layout: [lane&15][quad*8+j].
// ---------------------------------------------------------------------------
__global__ __launch_bounds__(256) void attn_mfma_kernel(
    const unsigned short* __restrict__ q_hi, const unsigned short* __restrict__ q_lo,
    const unsigned short* __restrict__ k_hi, const unsigned short* __restrict__ k_lo,
    const unsigned short* __restrict__ v_hi, const int* __restrict__ mask,
    float* __restrict__ scores, float* __restrict__ concat)
{
    // +8 pad (16B) keeps b128 alignment; row stride 144B -> 2-way bank alias (free)
    __shared__ __align__(16) unsigned short sQh[64][72], sQl[64][72];
    __shared__ __align__(16) unsigned short sKh[64][72], sKl[64][72];
    __shared__ __align__(16) unsigned short sVt[64][72];  // [dk][kpos]
    __shared__ __align__(16) unsigned short sP[64][72];   // [qrow][kpos]

    const int tid = threadIdx.x;
    const int q0 = blockIdx.x * 64;
    const int h = blockIdx.y, b = blockIdx.z;
    const size_t bh = (size_t)b * H_ + h;
    const int wv = tid >> 6, lane = tid & 63, quad = lane >> 4, col = lane & 15;

    const int sr = tid >> 2, sc = (tid & 3) * 16;   // staging row / col base

    // ---- stage Q tile (hi+lo), once ----
    {
        const u16x8* gh = (const u16x8*)(q_hi + (bh * S_ + q0 + sr) * DK_ + sc);
        const u16x8* gl = (const u16x8*)(q_lo + (bh * S_ + q0 + sr) * DK_ + sc);
        *(u16x8*)&sQh[sr][sc] = gh[0]; *(u16x8*)&sQh[sr][sc + 8] = gh[1];
        *(u16x8*)&sQl[sr][sc] = gl[0]; *(u16x8*)&sQl[sr][sc + 8] = gl[1];
    }

    const int* mbase = mask + (size_t)b * S_ * S_;

    // computes the wave's 16x64 S-tile for k-tile kt into sv[t][r]
    auto compute_svals = [&](int kt, float sv[4][4]) {
        #pragma unroll
        for (int t = 0; t < 4; ++t) {
            f32x4 acc = {0.f, 0.f, 0.f, 0.f};
            #pragma unroll
            for (int kc = 0; kc < 64; kc += 32) {
                bf16x8 ah = ldfrag(&sQh[wv * 16 + col][kc + quad * 8]);
                bf16x8 al = ldfrag(&sQl[wv * 16 + col][kc + quad * 8]);
                bf16x8 bh = ldfrag(&sKh[t * 16 + col][kc + quad * 8]);
                bf16x8 bl = ldfrag(&sKl[t * 16 + col][kc + quad * 8]);
                acc = __builtin_amdgcn_mfma_f32_16x16x32_bf16(ah, bh, acc, 0, 0, 0);
                acc = __builtin_amdgcn_mfma_f32_16x16x32_bf16(ah, bl, acc, 0, 0, 0);
                acc = __builtin_amdgcn_mfma_f32_16x16x32_bf16(al, bh, acc, 0, 0, 0);
            }
            #pragma unroll
            for (int r = 0; r < 4; ++r) {
                const int qg = q0 + wv * 16 + quad * 4 + r;
                const int kg = kt * 64 + t * 16 + col;
                float s = acc[r] * 0.125f;
                if (mbase[(size_t)qg * S_ + kg] == 0) s = -1e9f;
                sv[t][r] = s;
            }
        }
    };

    // ---- pass 1: row max & sum ----
    float m_run[4], l_run[4];
    #pragma unroll
    for (int r = 0; r < 4; ++r) { m_run[r] = -1e30f; l_run[r] = 0.f; }

    for (int kt = 0; kt < 32; ++kt) {
        __syncthreads();
        {
            const u16x8* gh = (const u16x8*)(k_hi + (bh * S_ + kt * 64 + sr) * DK_ + sc);
            const u16x8* gl = (const u16x8*)(k_lo + (bh * S_ + kt * 64 + sr) * DK_ + sc);
            *(u16x8*)&sKh[sr][sc] = gh[0]; *(u16x8*)&sKh[sr][sc + 8] = gh[1];
            *(u16x8*)&sKl[sr][sc] = gl[0]; *(u16x8*)&sKl[sr][sc + 8] = gl[1];
        }
        __syncthreads();
        float sv[4][4];
        compute_svals(kt, sv);
        #pragma unroll
        for (int r = 0; r < 4; ++r) {
            float tm = fmaxf(fmaxf(sv[0][r], sv[1][r]), fmaxf(sv[2][r], sv[3][r]));
            #pragma unroll
            for (int mm = 1; mm < 16; mm <<= 1) tm = fmaxf(tm, __shfl_xor(tm, mm));
            const float nm = fmaxf(m_run[r], tm);
            float ts = __expf(sv[0][r] - nm) + __expf(sv[1][r] - nm)
                     + __expf(sv[2][r] - nm) + __expf(sv[3][r] - nm);
            #pragma unroll
            for (int mm = 1; mm < 16; mm <<= 1) ts += __shfl_xor(ts, mm);
            l_run[r] = l_run[r] * __expf(m_run[r] - nm) + ts;
            m_run[r] = nm;
        }
    }
    float inv_l[4];
    #pragma unroll
    for (int r = 0; r < 4; ++r) inv_l[r] = 1.f / l_run[r];

    // ---- pass 2: recompute S, write scores, accumulate P@V ----
    f32x4 oacc[4] = {};
    for (int kt = 0; kt < 32; ++kt) {
        __syncthreads();
        {
            const u16x8* gh = (const u16x8*)(k_hi + (bh * S_ + kt * 64 + sr) * DK_ + sc);
            const u16x8* gl = (const u16x8*)(k_lo + (bh * S_ + kt * 64 + sr) * DK_ + sc);
            *(u16x8*)&sKh[sr][sc] = gh[0]; *(u16x8*)&sKh[sr][sc + 8] = gh[1];
            *(u16x8*)&sKl[sr][sc] = gl[0]; *(u16x8*)&sKl[sr][sc + 8] = gl[1];
            const u16x8* gv = (const u16x8*)(v_hi + (bh * S_ + kt * 64 + sr) * DK_ + sc);
            u16x8 a0 = gv[0], a1 = gv[1];
            #pragma unroll
            for (int i = 0; i < 8; ++i) { sVt[sc + i][sr] = a0[i]; sVt[sc + 8 + i][sr] = a1[i]; }
        }
        __syncthreads();
        float sv[4][4];
        compute_svals(kt, sv);
        #pragma unroll
        for (int t = 0; t < 4; ++t) {
            #pragma unroll
            for (int r = 0; r < 4; ++r) {
                const int qg = q0 + wv * 16 + quad * 4 + r;
                const int kg = kt * 64 + t * 16 + col;
                const float p = __expf(sv[t][r] - m_run[r]) * inv_l[r];
                scores[(bh * S_ + qg) * S_ + kg] = p;
                sP[wv * 16 + quad * 4 + r][t * 16 + col] = f2bf(p);
            }
        }
        // P@V: sP written & read by the SAME wave only (rows partitioned by wave);
        // per-wave LDS ops are in-order, no cross-wave barrier needed.
        #pragma unroll
        for (int to = 0; to < 4; ++to) {
            #pragma unroll
            for (int kc = 0; kc < 64; kc += 32) {
                bf16x8 a  = ldfrag(&sP[wv * 16 + col][kc + quad * 8]);
                bf16x8 bb = ldfrag(&sVt[to * 16 + col][kc + quad * 8]);
                oacc[to] = __builtin_amdgcn_mfma_f32_16x16x32_bf16(a, bb, oacc[to], 0, 0, 0);
            }
        }
    }

    // ---- epilogue: O -> concat [B,S,D] ----
    #pragma unroll
    for (int to = 0; to < 4; ++to) {
        #pragma unroll
        for (int r = 0; r < 4; ++r) {
            const int qg = q0 + wv * 16 + quad * 4 + r;
            concat[((size_t)b * S_ + qg) * D_ + h * DK_ + to * 16 + col] = oacc[to][r];
        }
    }
}

// ---------------------------------------------------------------------------
extern "C" void kernel_launch(void* const* d_in, const int* in_sizes, int n_in,
                              void* d_out, int out_size, void* d_ws, size_t ws_size,
                              hipStream_t stream) {
    const float* q  = (const float*)d_in[0];
    const float* k  = (const float*)d_in[1];
    const float* v  = (const float*)d_in[2];
    const int* mask = (const int*)d_in[3];
    const float* Wq = (const float*)d_in[4];  const float* bq = (const float*)d_in[5];
    const float* Wk = (const float*)d_in[6];  const float* bk = (const float*)d_in[7];
    const float* Wv = (const float*)d_in[8];  const float* bv = (const float*)d_in[9];
    const float* Wo = (const float*)d_in[10]; const float* bo = (const float*)d_in[11];

    float* out    = (float*)d_out;                 // [B,S,D]
    float* scores = out + (size_t)B_ * S_ * D_;    // [B,H,S,S]

    const size_t NH = (size_t)B_ * H_ * S_ * DK_;  // 4.19M elements
    unsigned short* q_hi = (unsigned short*)d_ws;
    unsigned short* q_lo = q_hi + NH;
    unsigned short* k_hi = q_lo + NH;
    unsigned short* k_lo = k_hi + NH;
    unsigned short* v_hi = k_lo + NH;
    float* concat = (float*)(v_hi + NH);           // [B,S,D] fp32
    // ws use: 5 * 8.39 MB + 16.8 MB ~= 58.7 MB

    dim3 gg(M_ / 64, D_ / 64);   // 128 x 8
    proj_kernel<<<gg, 256, 0, stream>>>(q, Wq, bq, nullptr, q_hi, q_lo, 1);
    proj_kernel<<<gg, 256, 0, stream>>>(k, Wk, bk, nullptr, k_hi, k_lo, 1);
    proj_kernel<<<gg, 256, 0, stream>>>(v, Wv, bv, nullptr, v_hi, nullptr, 2);
    attn_mfma_kernel<<<dim3(S_ / 64, H_, B_), 256, 0, stream>>>(
        q_hi, q_lo, k_hi, k_lo, v_hi, mask, scores, concat);
    proj_kernel<<<gg, 256, 0, stream>>>(concat, Wo, bo, out, nullptr, nullptr, 0);
}